// Round 10
// baseline (385.131 us; speedup 1.0000x reference)
//
#include <hip/hip_runtime.h>
#include <hip/hip_bf16.h>
#include <math.h>

#define HID 128
#define PR 20     // rows per pool block (divides 10000/5000/2500)
#define CRPB 32   // conv rows per block
#define RCAP 6144 // radix candidate cap
#define MAXCELLS 4096

// ---------- fused mean-gather + GraphConv + score-scalar epilogue ----------
// 128 threads (2 waves). Thread owns 4 consecutive cols (q*4..q*4+3) x 8 rows.
// CRPB=32: grid 625/313/157 blocks; LDS 33KB -> 4 blocks/CU; threads/row=4 ->
// weight L2 traffic ~80MB at l0 (L1 catches intra-block duplicates).
template <int K>
__global__ __launch_bounds__(128) void k_conv_fused(
    const float* __restrict__ x, const int* __restrict__ src, int n, float invk,
    const float* __restrict__ Wrel, const float* __restrict__ Wroot,
    const float* __restrict__ brel,
    const float* __restrict__ wprel, const float* __restrict__ wproot,
    float* __restrict__ out, float* __restrict__ uo, float* __restrict__ vo) {
  __shared__ float4 sagg4[CRPB][HID / 4];
  __shared__ float4 sx4[CRPB][HID / 4];
  __shared__ int ssrc[CRPB * K];
  int t = threadIdx.x;
  int i0 = blockIdx.x * CRPB;
  const int nK = n * K;
  for (int s = t; s < CRPB * K; s += 128) {
    int gi = i0 * K + s;
    int v = (gi < nK) ? src[gi] : 0;
    ssrc[s] = ((unsigned)v < (unsigned)n) ? v : 0;
  }
  __syncthreads();
  {
    int fq = t & 31, h = t >> 5;                // col quad, row slot (4 slots)
    const float4* x4 = (const float4*)x;
    for (int r = h; r < CRPB; r += 4) {
      int row = i0 + r;
      float4 s = make_float4(0.f, 0.f, 0.f, 0.f);
      float4 xv = make_float4(0.f, 0.f, 0.f, 0.f);
      if (row < n) {
#pragma unroll
        for (int j = 0; j < K; ++j) {
          float4 xx = x4[(size_t)ssrc[r * K + j] * 32 + fq];
          s.x += xx.x; s.y += xx.y; s.z += xx.z; s.w += xx.w;
        }
        xv = x4[(size_t)row * 32 + fq];
      }
      s.x *= invk; s.y *= invk; s.z *= invk; s.w *= invk;
      sagg4[r][fq] = s;
      sx4[r][fq] = xv;
    }
  }
  __syncthreads();
  int q = t & 31, rg = t >> 5;                  // col quad; row group (rows rg*8..rg*8+7)
  const float4* Wrel4  = (const float4*)Wrel;
  const float4* Wroot4 = (const float4*)Wroot;
  float4 bq = ((const float4*)brel)[q];
  float4 acc[8];
#pragma unroll
  for (int rr = 0; rr < 8; ++rr) acc[rr] = bq;
  int rbase = rg * 8;
#pragma unroll 2
  for (int cq = 0; cq < HID / 4; ++cq) {
    float4 w1[4], w2[4];
#pragma unroll
    for (int uu = 0; uu < 4; ++uu) {
      w1[uu] = Wrel4[(cq * 4 + uu) * 32 + q];
      w2[uu] = Wroot4[(cq * 4 + uu) * 32 + q];
    }
#pragma unroll
    for (int rr = 0; rr < 8; ++rr) {
      float4 a  = sagg4[rbase + rr][cq];
      float4 xx = sx4[rbase + rr][cq];
      acc[rr].x += a.x*w1[0].x + a.y*w1[1].x + a.z*w1[2].x + a.w*w1[3].x
                 + xx.x*w2[0].x + xx.y*w2[1].x + xx.z*w2[2].x + xx.w*w2[3].x;
      acc[rr].y += a.x*w1[0].y + a.y*w1[1].y + a.z*w1[2].y + a.w*w1[3].y
                 + xx.x*w2[0].y + xx.y*w2[1].y + xx.z*w2[2].y + xx.w*w2[3].y;
      acc[rr].z += a.x*w1[0].z + a.y*w1[1].z + a.z*w1[2].z + a.w*w1[3].z
                 + xx.x*w2[0].z + xx.y*w2[1].z + xx.z*w2[2].z + xx.w*w2[3].z;
      acc[rr].w += a.x*w1[0].w + a.y*w1[1].w + a.z*w1[2].w + a.w*w1[3].w
                 + xx.x*w2[0].w + xx.y*w2[1].w + xx.z*w2[2].w + xx.w*w2[3].w;
    }
  }
  float4 wplq = ((const float4*)wprel)[q];
  float4 wprq = ((const float4*)wproot)[q];
#pragma unroll
  for (int rr = 0; rr < 8; ++rr) {
    int row = i0 + rbase + rr;
    float4 v = acc[rr];
    v.x = v.x > 0.f ? v.x : 0.f;
    v.y = v.y > 0.f ? v.y : 0.f;
    v.z = v.z > 0.f ? v.z : 0.f;
    v.w = v.w > 0.f ? v.w : 0.f;
    float pu = 0.f, pv = 0.f;
    if (row < n) {
      ((float4*)out)[(size_t)row * 32 + q] = v;
      pu = v.x * wplq.x + v.y * wplq.y + v.z * wplq.z + v.w * wplq.w;
      pv = v.x * wprq.x + v.y * wprq.y + v.z * wprq.z + v.w * wprq.w;
    }
#pragma unroll
    for (int o = 16; o; o >>= 1) {
      pu += __shfl_down(pu, o, 32);
      pv += __shfl_down(pv, o, 32);
    }
    if (q == 0 && row < n) { uo[row] = pu; vo[row] = pv; }
  }
}

// ---------- scalar score: score_i = tanh( sum_j u[src] + v_i + b ) ----------
template <int K>
__global__ void k_score_lite(const float* __restrict__ u, const float* __restrict__ v,
                             const int* __restrict__ src, const float* __restrict__ bprel,
                             int n, float* __restrict__ score, unsigned* __restrict__ key) {
  int i = blockIdx.x * blockDim.x + threadIdx.x;
  if (i >= n) return;
  float s = v[i] + bprel[0];
#pragma unroll
  for (int j = 0; j < K; ++j) s += u[src[i * K + j]];
  float sc = tanhf(s);
  score[i] = sc;
  unsigned bb = __float_as_uint(sc);
  key[i] = (bb & 0x80000000u) ? ~bb : (bb | 0x80000000u);
}

// ---------- mega-select: radix top-k threshold + ordered compaction + grid build ----------
// Single block, 1024 threads. Phases:
//  P1 1024-bin histogram; P2 bin pick; P3 candidate refine (exact T = kth key, Gt = #>T)
//  P4 ballot-ordered compaction -> perm[0..Gt) = gt (index-asc), perm[Gt..kk) = lowest eq
//  P5-7 (cells>0): LDS cell count -> scan -> scatter (spos/sidx/starts/counts for knn)
__global__ __launch_bounds__(1024) void k_select(
    const unsigned* __restrict__ key, int n, int kk,
    const float* __restrict__ pos_in, int* __restrict__ perm,
    int* __restrict__ startsg, int* __restrict__ countsg,
    float2* __restrict__ spos, int* __restrict__ sidx,
    int cells, int Gg, float inv_w) {
  __shared__ unsigned hist[1024];
  __shared__ int sscan[1024];
  __shared__ unsigned cand[RCAP];
  __shared__ unsigned hist256[256];
  __shared__ int lcnt[MAXCELLS];
  __shared__ int lcur[MAXCELLS];
  __shared__ unsigned sh_B, sh_above, sh_cnt, sh_remain, sh_prefix;
  __shared__ int wsum_g[16], wsum_e[16];
  __shared__ int sh_bg, sh_be;
  int t = threadIdx.x;

  // ---- P1: 1024-bin histogram over top 10 bits ----
  hist[t] = 0u;
  if (t == 0) sh_cnt = 0u;
  __syncthreads();
  const uint4* key4 = (const uint4*)key;
  int n4 = n >> 2;                        // n divisible by 4
  for (int i = t; i < n4; i += 1024) {
    uint4 kv = key4[i];
    atomicAdd(&hist[kv.x >> 22], 1u);
    atomicAdd(&hist[kv.y >> 22], 1u);
    atomicAdd(&hist[kv.z >> 22], 1u);
    atomicAdd(&hist[kv.w >> 22], 1u);
  }
  __syncthreads();
  // ---- P2: inclusive scan (desc semantics), pick boundary bin ----
  unsigned v = hist[t];
  unsigned val = v;
  sscan[t] = (int)val;
  __syncthreads();
  for (int off = 1; off < 1024; off <<= 1) {
    unsigned o = (t >= off) ? (unsigned)sscan[t - off] : 0u;
    __syncthreads();
    val += o;
    sscan[t] = (int)val;
    __syncthreads();
  }
  unsigned total = (unsigned)sscan[1023];
  unsigned above_strict = total - val;
  unsigned above_incl = above_strict + v;
  if (above_incl >= (unsigned)kk && above_strict < (unsigned)kk) {
    sh_B = (unsigned)t;
    sh_above = above_strict;
  }
  __syncthreads();
  unsigned B = sh_B, above = sh_above;
  int remain = kk - (int)above;           // 1 <= remain <= hist[B]
  // ---- P3: collect bin-B candidates, 4-pass byte refine ----
  for (int i = t; i < n4; i += 1024) {
    uint4 kv = key4[i];
    if ((kv.x >> 22) == B) { unsigned p = atomicAdd(&sh_cnt, 1u); if (p < RCAP) cand[p] = kv.x; }
    if ((kv.y >> 22) == B) { unsigned p = atomicAdd(&sh_cnt, 1u); if (p < RCAP) cand[p] = kv.y; }
    if ((kv.z >> 22) == B) { unsigned p = atomicAdd(&sh_cnt, 1u); if (p < RCAP) cand[p] = kv.z; }
    if ((kv.w >> 22) == B) { unsigned p = atomicAdd(&sh_cnt, 1u); if (p < RCAP) cand[p] = kv.w; }
  }
  __syncthreads();
  int cnt = (int)sh_cnt; if (cnt > RCAP) cnt = RCAP;
  if (t == 0) { sh_prefix = 0u; sh_remain = (unsigned)remain; }
  __syncthreads();
  for (int pass = 0; pass < 4; ++pass) {
    int shift = 24 - pass * 8;
    if (t < 256) hist256[t] = 0u;
    __syncthreads();
    unsigned prefix = sh_prefix;
    unsigned himask = (pass == 0) ? 0u : (0xFFFFFFFFu << (shift + 8));
    for (int i = t; i < cnt; i += 1024) {
      unsigned kky = cand[i];
      if ((kky & himask) == prefix) atomicAdd(&hist256[(kky >> shift) & 255u], 1u);
    }
    __syncthreads();
    if (t == 0) {
      unsigned rem = sh_remain;
      int b = 255;
      for (; b > 0; --b) {
        unsigned c = hist256[b];
        if (rem > c) rem -= c; else break;
      }
      sh_prefix = prefix | ((unsigned)b << shift);
      sh_remain = rem;
    }
    __syncthreads();
  }
  unsigned T = sh_prefix;
  int Gt = (int)(above + (unsigned)remain - sh_remain);   // #{key > T}
  int need = kk - Gt;
  // ---- P4: ballot-ordered compaction (index-ascending, deterministic) ----
  if (t == 0) { sh_bg = 0; sh_be = 0; }
  __syncthreads();
  int lane = t & 63, wid = t >> 6;
  unsigned long long lmask = (1ull << lane) - 1ull;
  for (int start = 0; start < n; start += 1024) {
    int i = start + t;
    unsigned kv = (i < n) ? key[i] : 0u;
    bool g = (i < n) && (kv > T);
    bool e = (i < n) && (kv == T);
    unsigned long long mg = __ballot(g);
    unsigned long long me = __ballot(e);
    if (lane == 0) { wsum_g[wid] = __popcll(mg); wsum_e[wid] = __popcll(me); }
    __syncthreads();
    int pg = 0, pe = 0, tot_g = 0, tot_e = 0;
#pragma unroll
    for (int w2 = 0; w2 < 16; ++w2) {
      int sg = wsum_g[w2], se = wsum_e[w2];
      if (w2 < wid) { pg += sg; pe += se; }
      tot_g += sg; tot_e += se;
    }
    int bg = sh_bg, be = sh_be;
    __syncthreads();                       // everyone captured bases
    if (t == 0) { sh_bg = bg + tot_g; sh_be = be + tot_e; }
    if (g) perm[bg + pg + __popcll(mg & lmask)] = i;
    if (e) {
      int ep = be + pe + __popcll(me & lmask);
      if (ep < need) perm[Gt + ep] = i;
    }
    __syncthreads();                       // base update visible before next iter
  }
  __syncthreads();
  // ---- P5-7: grid build for KNN (skip on last layer) ----
  if (cells > 0) {
    for (int c = t; c < cells; c += 1024) lcnt[c] = 0;
    __syncthreads();
    for (int j = t; j < kk; j += 1024) {
      int node = perm[j];
      float px = pos_in[node * 2], py = pos_in[node * 2 + 1];
      int cx = min(Gg - 1, max(0, (int)(px * inv_w)));
      int cy = min(Gg - 1, max(0, (int)(py * inv_w)));
      atomicAdd(&lcnt[cy * Gg + cx], 1);
    }
    __syncthreads();
    // scan cells (4 per thread)
    {
      int c0[4]; int base = t * 4; int s = 0;
#pragma unroll
      for (int u = 0; u < 4; ++u) {
        int idx = base + u;
        c0[u] = (idx < cells) ? lcnt[idx] : 0;
        s += c0[u];
      }
      sscan[t] = s;
      __syncthreads();
      int vv = s;
      for (int off = 1; off < 1024; off <<= 1) {
        int o = (t >= off) ? sscan[t - off] : 0;
        __syncthreads();
        vv += o;
        sscan[t] = vv;
        __syncthreads();
      }
      int excl = vv - s;
#pragma unroll
      for (int u = 0; u < 4; ++u) {
        int idx = base + u;
        if (idx < cells) { startsg[idx] = excl; lcur[idx] = excl; countsg[idx] = c0[u]; excl += c0[u]; }
      }
    }
    __syncthreads();
    for (int j = t; j < kk; j += 1024) {
      int node = perm[j];
      float px = pos_in[node * 2], py = pos_in[node * 2 + 1];
      int cx = min(Gg - 1, max(0, (int)(px * inv_w)));
      int cy = min(Gg - 1, max(0, (int)(py * inv_w)));
      int pp = atomicAdd(&lcur[cy * Gg + cx], 1);
      spos[pp] = make_float2(px, py);
      sidx[pp] = j;
    }
  }
}

// ---------- pooled gather + per-block column-max ----------
template <int R>
__global__ __launch_bounds__(256) void k_pool_pmax(
    const float* __restrict__ x, const float* __restrict__ score,
    const int* __restrict__ perm, const float* __restrict__ pos_in,
    float* __restrict__ xout, float* __restrict__ pos_out, int store,
    float* __restrict__ pmax) {
  __shared__ float sm[2][HID];
  int f = threadIdx.x & 127;
  int half = threadIdx.x >> 7;
  int j0 = blockIdx.x * R;
  float mx = -1e30f;
  for (int r = half; r < R; r += 2) {
    int j = j0 + r;
    int node = perm[j];
    float v = score[node];
    float val = x[(size_t)node * HID + f] * v;
    if (store) {
      xout[(size_t)j * HID + f] = val;
      if (f < 2) pos_out[j * 2 + f] = pos_in[node * 2 + f];
    }
    mx = fmaxf(mx, val);
  }
  sm[half][f] = mx;
  __syncthreads();
  if (half == 0) pmax[blockIdx.x * HID + f] = fmaxf(sm[0][f], sm[1][f]);
}

// ---------- exact KNN, one wave per query ----------
template <int K>
__global__ __launch_bounds__(256) void k_knn_wave(const float2* __restrict__ spos,
                           const int* __restrict__ sidx,
                           const int* __restrict__ starts, const int* __restrict__ counts,
                           int m, int G, float w, float inv_w, int* __restrict__ src_out) {
  int lane = threadIdx.x & 63;
  int j = blockIdx.x * (blockDim.x >> 6) + (threadIdx.x >> 6);
  if (j >= m) return;                      // wave-uniform exit
  float2 qp = spos[j];
  int q = sidx[j];
  int cx = min(G - 1, max(0, (int)(qp.x * inv_w)));
  int cy = min(G - 1, max(0, (int)(qp.y * inv_w)));

  float bd[K]; int bi[K];
#pragma unroll
  for (int t = 0; t < K; ++t) { bd[t] = 1e30f; bi[t] = 0; }

  auto scan_span = [&](int s, int e) {
    for (int p = s + lane; p < e; p += 64) {
      if (p == j) continue;                // self (loop=False)
      float2 pp = spos[p];
      float dx = qp.x - pp.x, dy = qp.y - pp.y;
      float d = dx * dx + dy * dy;
      if (d < bd[K - 1]) {
        float dd = d; int ii = sidx[p];
#pragma unroll
        for (int t = 0; t < K; ++t) {
          bool sw = dd < bd[t];
          float od = bd[t]; int oi = bi[t];
          if (sw) { bd[t] = dd; bi[t] = ii; dd = od; ii = oi; }
        }
      }
    }
  };

  {
    int xl = max(0, cx - 1), xh = min(G - 1, cx + 1);
    int y0 = max(0, cy - 1), y1 = min(G - 1, cy + 1);
    int ss[3], ee[3]; int nr = 0;
    for (int y = y0; y <= y1; ++y) {
      int b = y * G;
      ss[nr] = starts[b + xl];
      ee[nr] = starts[b + xh] + counts[b + xh];
      ++nr;
    }
    for (int t = 0; t < nr; ++t) scan_span(ss[t], ee[t]);
  }

  int r = 1;
  unsigned long long mg[K];
  while (true) {
    unsigned long long tmp[K];
#pragma unroll
    for (int t = 0; t < K; ++t)
      tmp[t] = ((unsigned long long)__float_as_uint(bd[t]) << 32) | (unsigned)bi[t];
#pragma unroll
    for (int t = 0; t < K; ++t) {
      unsigned long long mn = tmp[0];
#pragma unroll
      for (int o = 1; o < 64; o <<= 1) {
        unsigned long long ot = __shfl_xor(mn, o, 64);
        if (ot < mn) mn = ot;
      }
      mg[t] = mn;
      if (tmp[0] == mn) {
#pragma unroll
        for (int s2 = 0; s2 < K - 1; ++s2) tmp[s2] = tmp[s2 + 1];
        tmp[K - 1] = ~0ull;
      }
    }
    float kth = __uint_as_float((unsigned)(mg[K - 1] >> 32));
    float bnd = 1e30f;
    if (cx - r > 0)     bnd = fminf(bnd, qp.x - (float)(cx - r) * w);
    if (cx + r < G - 1) bnd = fminf(bnd, (float)(cx + r + 1) * w - qp.x);
    if (cy - r > 0)     bnd = fminf(bnd, qp.y - (float)(cy - r) * w);
    if (cy + r < G - 1) bnd = fminf(bnd, (float)(cy + r + 1) * w - qp.y);
    if (bnd > 1e29f) break;                // grid exhausted
    float bb = fmaxf(bnd, 0.f) * 0.999f;
    if (kth < bb * bb) break;
    ++r;
    int xl = max(0, cx - r), xh = min(G - 1, cx + r);
    int yt = cy - r, yb = cy + r;
    if (yt >= 0)     { int b = yt * G; scan_span(starts[b + xl], starts[b + xh] + counts[b + xh]); }
    if (yb <= G - 1) { int b = yb * G; scan_span(starts[b + xl], starts[b + xh] + counts[b + xh]); }
    int ylo = max(0, cy - r + 1), yhi = min(G - 1, cy + r - 1);
    for (int y = ylo; y <= yhi; ++y) {
      int b = y * G;
      if (cx - r >= 0)     { int c = b + cx - r; scan_span(starts[c], starts[c] + counts[c]); }
      if (cx + r <= G - 1) { int c = b + cx + r; scan_span(starts[c], starts[c] + counts[c]); }
    }
  }
  if (lane == 0) {
#pragma unroll
    for (int t = 0; t < K; ++t) src_out[q * K + t] = (int)(unsigned)(mg[t] & 0xffffffffu);
  }
}

// ---------- final: reduce pmax segments -> xs, then MLP head ----------
__global__ __launch_bounds__(1024) void k_final(const float* __restrict__ pmax,
                        int P0, int P1, int P2,
                        const float* __restrict__ W1, const float* __restrict__ b1,
                        const float* __restrict__ W2, const float* __restrict__ b2,
                        float* __restrict__ out) {
  __shared__ float red[8][HID];
  __shared__ float sxs[3 * HID];
  __shared__ float h1[HID];
  int f = threadIdx.x & 127, ch = threadIdx.x >> 7;   // 1024 threads
  int off0 = 0, off1 = P0, off2 = P0 + P1, off3 = P0 + P1 + P2;
  int lo[3] = {off0, off1, off2};
  int hi[3] = {off1, off2, off3};
  for (int l = 0; l < 3; ++l) {
    float mx = -1e30f;
    for (int p = lo[l] + ch; p < hi[l]; p += 8) mx = fmaxf(mx, pmax[p * HID + f]);
    red[ch][f] = mx;
    __syncthreads();
    if (ch == 0) {
      float m2 = red[0][f];
#pragma unroll
      for (int u = 1; u < 8; ++u) m2 = fmaxf(m2, red[u][f]);
      sxs[l * HID + f] = m2;
    }
    __syncthreads();
  }
  if (threadIdx.x < HID) {
    float acc = b1[f];
    for (int c = 0; c < 3 * HID; ++c) acc += sxs[c] * W1[c * HID + f];
    h1[f] = acc > 0.f ? acc : 0.f;
  }
  __syncthreads();
  if (threadIdx.x < 5) {
    float a = b2[threadIdx.x];
    for (int c = 0; c < HID; ++c) a += h1[c] * W2[c * 5 + threadIdx.x];
    out[threadIdx.x] = a;
  }
}

extern "C" void kernel_launch(void* const* d_in, const int* in_sizes, int n_in,
                              void* d_out, int out_size, void* d_ws, size_t ws_size,
                              hipStream_t stream) {
  const float* x_in   = (const float*)d_in[0];
  const float* pos_in = (const float*)d_in[1];
  const int*   ei     = (const int*)d_in[2];
  const float* Wrel   = (const float*)d_in[3];
  const float* brel   = (const float*)d_in[4];
  const float* Wroot  = (const float*)d_in[5];
  const float* Wprel  = (const float*)d_in[6];
  const float* bprel  = (const float*)d_in[7];
  const float* Wproot = (const float*)d_in[8];
  const float* W1     = (const float*)d_in[9];
  const float* b1     = (const float*)d_in[10];
  const float* W2     = (const float*)d_in[11];
  const float* b2     = (const float*)d_in[12];
  float* out = (float*)d_out;

  const int N0 = in_sizes[0] / HID;   // 20000
  const int P0 = (N0 / 2) / PR, P1 = (N0 / 4) / PR, P2 = (N0 / 8) / PR;  // 500/250/125

  // workspace layout (16B-aligned regions)
  char* w = (char*)d_ws;
  float*    xB     = (float*)w;    w += (size_t)N0 * HID * 4;
  float*    xA     = (float*)w;    w += (size_t)(N0 / 2) * HID * 4;
  float*    score  = (float*)w;    w += (size_t)N0 * 4;
  unsigned* key    = (unsigned*)w; w += (size_t)N0 * 4;
  float*    ubuf   = (float*)w;    w += (size_t)N0 * 4;
  float*    vbuf   = (float*)w;    w += (size_t)N0 * 4;
  float*    posA   = (float*)w;    w += (size_t)(N0 / 2) * 2 * 4;
  float*    posB   = (float*)w;    w += (size_t)(N0 / 2) * 2 * 4;
  int*      srcbuf = (int*)w;      w += (size_t)(N0 / 2) * 8 * 4;
  int*      permb  = (int*)w;      w += (size_t)(N0 / 2) * 4;
  float*    pmax   = (float*)w;    w += (size_t)(P0 + P1 + P2) * HID * 4;
  int*      counts = (int*)w;      w += MAXCELLS * 4;
  int*      starts = (int*)w;      w += MAXCELLS * 4;
  float2*   spos   = (float2*)w;   w += (size_t)(N0 / 2) * 8;
  int*      sidx   = (int*)w;      w += (size_t)(N0 / 2) * 4;
  (void)ws_size; (void)n_in; (void)out_size;

  int n = N0;
  const float* xcur   = x_in;
  const float* poscur = pos_in;
  const int*   srccur = ei;
  int kcur = 6;                 // E0/N0 == 6 (K0)
  int Poff = 0;

  for (int l = 0; l < 3; ++l) {
    const int kk = n / 2;
    int Gg = (int)ceilf(sqrtf((float)kk / 2.5f));
    if (Gg > 64) Gg = 64;
    if (Gg < 1) Gg = 1;
    int cells = Gg * Gg;
    float cw = 100.f / (float)Gg;
    float inv_w = (float)Gg / 100.f;
    int cblocks = (n + CRPB - 1) / CRPB;

    if (kcur == 6) {
      k_conv_fused<6><<<cblocks, 128, 0, stream>>>(xcur, srccur, n, 1.f / 6.f,
          Wrel + l * HID * HID, Wroot + l * HID * HID, brel + l * HID,
          Wprel + l * HID, Wproot + l * HID, xB, ubuf, vbuf);
      k_score_lite<6><<<(n + 255) / 256, 256, 0, stream>>>(ubuf, vbuf, srccur, bprel + l,
                                                           n, score, key);
    } else {
      k_conv_fused<8><<<cblocks, 128, 0, stream>>>(xcur, srccur, n, 1.f / 8.f,
          Wrel + l * HID * HID, Wroot + l * HID * HID, brel + l * HID,
          Wprel + l * HID, Wproot + l * HID, xB, ubuf, vbuf);
      k_score_lite<8><<<(n + 255) / 256, 256, 0, stream>>>(ubuf, vbuf, srccur, bprel + l,
                                                           n, score, key);
    }
    // mega-select: topk threshold + perm + (grid count/scan/scatter for knn)
    k_select<<<1, 1024, 0, stream>>>(key, n, kk, poscur, permb, starts, counts,
                                     spos, sidx, (l < 2) ? cells : 0, Gg, inv_w);
    float* pos_out = (l == 0) ? posA : posB;
    int store = (l < 2) ? 1 : 0;
    k_pool_pmax<PR><<<kk / PR, 256, 0, stream>>>(xB, score, permb, poscur, xA, pos_out,
                                                 store, pmax + (size_t)Poff * HID);
    Poff += kk / PR;
    n = kk;
    if (l == 0)      { k_knn_wave<6><<<(n + 3) / 4, 256, 0, stream>>>(spos, sidx, starts, counts,
                                                                      n, Gg, cw, inv_w, srcbuf); kcur = 6; }
    else if (l == 1) { k_knn_wave<8><<<(n + 3) / 4, 256, 0, stream>>>(spos, sidx, starts, counts,
                                                                      n, Gg, cw, inv_w, srcbuf); kcur = 8; }
    xcur = xA; poscur = pos_out; srccur = srcbuf;
  }
  k_final<<<1, 1024, 0, stream>>>(pmax, P0, P1, P2, W1, b1, W2, b2, out);
}

// Round 11
// 320.841 us; speedup vs baseline: 1.2004x; 1.2004x over previous
//
#include <hip/hip_runtime.h>
#include <hip/hip_bf16.h>
#include <math.h>

#define HID 128
#define PR 20     // rows per pool block (divides 10000/5000/2500)
#define CRPB 32   // conv rows per block
#define RCAP 6144 // radix candidate cap
#define MAXCELLS 4096

// ---------- fused mean-gather + GraphConv + score-scalar epilogue ----------
template <int K>
__global__ __launch_bounds__(128) void k_conv_fused(
    const float* __restrict__ x, const int* __restrict__ src, int n, float invk,
    const float* __restrict__ Wrel, const float* __restrict__ Wroot,
    const float* __restrict__ brel,
    const float* __restrict__ wprel, const float* __restrict__ wproot,
    float* __restrict__ out, float* __restrict__ uo, float* __restrict__ vo) {
  __shared__ float4 sagg4[CRPB][HID / 4];
  __shared__ float4 sx4[CRPB][HID / 4];
  __shared__ int ssrc[CRPB * K];
  int t = threadIdx.x;
  int i0 = blockIdx.x * CRPB;
  const int nK = n * K;
  for (int s = t; s < CRPB * K; s += 128) {
    int gi = i0 * K + s;
    int v = (gi < nK) ? src[gi] : 0;
    ssrc[s] = ((unsigned)v < (unsigned)n) ? v : 0;
  }
  __syncthreads();
  {
    int fq = t & 31, h = t >> 5;                // col quad, row slot (4 slots)
    const float4* x4 = (const float4*)x;
    for (int r = h; r < CRPB; r += 4) {
      int row = i0 + r;
      float4 s = make_float4(0.f, 0.f, 0.f, 0.f);
      float4 xv = make_float4(0.f, 0.f, 0.f, 0.f);
      if (row < n) {
#pragma unroll
        for (int j = 0; j < K; ++j) {
          float4 xx = x4[(size_t)ssrc[r * K + j] * 32 + fq];
          s.x += xx.x; s.y += xx.y; s.z += xx.z; s.w += xx.w;
        }
        xv = x4[(size_t)row * 32 + fq];
      }
      s.x *= invk; s.y *= invk; s.z *= invk; s.w *= invk;
      sagg4[r][fq] = s;
      sx4[r][fq] = xv;
    }
  }
  __syncthreads();
  int q = t & 31, rg = t >> 5;                  // col quad; row group (rows rg*8..rg*8+7)
  const float4* Wrel4  = (const float4*)Wrel;
  const float4* Wroot4 = (const float4*)Wroot;
  float4 bq = ((const float4*)brel)[q];
  float4 acc[8];
#pragma unroll
  for (int rr = 0; rr < 8; ++rr) acc[rr] = bq;
  int rbase = rg * 8;
#pragma unroll 2
  for (int cq = 0; cq < HID / 4; ++cq) {
    float4 w1[4], w2[4];
#pragma unroll
    for (int uu = 0; uu < 4; ++uu) {
      w1[uu] = Wrel4[(cq * 4 + uu) * 32 + q];
      w2[uu] = Wroot4[(cq * 4 + uu) * 32 + q];
    }
#pragma unroll
    for (int rr = 0; rr < 8; ++rr) {
      float4 a  = sagg4[rbase + rr][cq];
      float4 xx = sx4[rbase + rr][cq];
      acc[rr].x += a.x*w1[0].x + a.y*w1[1].x + a.z*w1[2].x + a.w*w1[3].x
                 + xx.x*w2[0].x + xx.y*w2[1].x + xx.z*w2[2].x + xx.w*w2[3].x;
      acc[rr].y += a.x*w1[0].y + a.y*w1[1].y + a.z*w1[2].y + a.w*w1[3].y
                 + xx.x*w2[0].y + xx.y*w2[1].y + xx.z*w2[2].y + xx.w*w2[3].y;
      acc[rr].z += a.x*w1[0].z + a.y*w1[1].z + a.z*w1[2].z + a.w*w1[3].z
                 + xx.x*w2[0].z + xx.y*w2[1].z + xx.z*w2[2].z + xx.w*w2[3].z;
      acc[rr].w += a.x*w1[0].w + a.y*w1[1].w + a.z*w1[2].w + a.w*w1[3].w
                 + xx.x*w2[0].w + xx.y*w2[1].w + xx.z*w2[2].w + xx.w*w2[3].w;
    }
  }
  float4 wplq = ((const float4*)wprel)[q];
  float4 wprq = ((const float4*)wproot)[q];
#pragma unroll
  for (int rr = 0; rr < 8; ++rr) {
    int row = i0 + rbase + rr;
    float4 v = acc[rr];
    v.x = v.x > 0.f ? v.x : 0.f;
    v.y = v.y > 0.f ? v.y : 0.f;
    v.z = v.z > 0.f ? v.z : 0.f;
    v.w = v.w > 0.f ? v.w : 0.f;
    float pu = 0.f, pv = 0.f;
    if (row < n) {
      ((float4*)out)[(size_t)row * 32 + q] = v;
      pu = v.x * wplq.x + v.y * wplq.y + v.z * wplq.z + v.w * wplq.w;
      pv = v.x * wprq.x + v.y * wprq.y + v.z * wprq.z + v.w * wprq.w;
    }
#pragma unroll
    for (int o = 16; o; o >>= 1) {
      pu += __shfl_down(pu, o, 32);
      pv += __shfl_down(pv, o, 32);
    }
    if (q == 0 && row < n) { uo[row] = pu; vo[row] = pv; }
  }
}

// ---------- scalar score: score_i = tanh( sum_j u[src] + v_i + b ) ----------
template <int K>
__global__ void k_score_lite(const float* __restrict__ u, const float* __restrict__ v,
                             const int* __restrict__ src, const float* __restrict__ bprel,
                             int n, float* __restrict__ score, unsigned* __restrict__ key) {
  int i = blockIdx.x * blockDim.x + threadIdx.x;
  if (i >= n) return;
  float s = v[i] + bprel[0];
#pragma unroll
  for (int j = 0; j < K; ++j) s += u[src[i * K + j]];
  float sc = tanhf(s);
  score[i] = sc;
  unsigned bb = __float_as_uint(sc);
  key[i] = (bb & 0x80000000u) ? ~bb : (bb | 0x80000000u);
}

// ---------- mega-select: all picks PARALLEL (no serial bin walks) ----------
__global__ __launch_bounds__(1024) void k_select(
    const unsigned* __restrict__ key, int n, int kk,
    const float* __restrict__ pos_in, int* __restrict__ perm,
    int* __restrict__ startsg, int* __restrict__ countsg,
    float2* __restrict__ spos, int* __restrict__ sidx,
    int cells, int Gg, float inv_w) {
  __shared__ unsigned hist[1024];
  __shared__ int sscan[1024];
  __shared__ unsigned cand[RCAP];
  __shared__ unsigned hist256[256];
  __shared__ int lcnt[MAXCELLS];
  __shared__ int lcur[MAXCELLS];
  __shared__ unsigned sh_B, sh_above, sh_cnt, sh_remain, sh_prefix;
  __shared__ int wsum_g[16], wsum_e[16];
  __shared__ int sh_bg, sh_be;
  int t = threadIdx.x;

  // ---- P1: 1024-bin histogram over top 10 bits ----
  hist[t] = 0u;
  if (t == 0) sh_cnt = 0u;
  __syncthreads();
  const uint4* key4 = (const uint4*)key;
  int n4 = n >> 2;                        // n divisible by 4
  for (int i = t; i < n4; i += 1024) {
    uint4 kv = key4[i];
    atomicAdd(&hist[kv.x >> 22], 1u);
    atomicAdd(&hist[kv.y >> 22], 1u);
    atomicAdd(&hist[kv.z >> 22], 1u);
    atomicAdd(&hist[kv.w >> 22], 1u);
  }
  __syncthreads();
  // ---- P2: parallel boundary-bin pick ----
  unsigned v = hist[t];
  unsigned val = v;
  sscan[t] = (int)val;
  __syncthreads();
  for (int off = 1; off < 1024; off <<= 1) {
    unsigned o = (t >= off) ? (unsigned)sscan[t - off] : 0u;
    __syncthreads();
    val += o;
    sscan[t] = (int)val;
    __syncthreads();
  }
  unsigned total = (unsigned)sscan[1023];
  unsigned above_strict = total - val;
  unsigned above_incl = above_strict + v;
  if (above_incl >= (unsigned)kk && above_strict < (unsigned)kk) {
    sh_B = (unsigned)t;
    sh_above = above_strict;
  }
  __syncthreads();
  unsigned B = sh_B, above = sh_above;
  int remain = kk - (int)above;           // 1 <= remain <= hist[B]
  // ---- P3: collect bin-B candidates ----
  for (int i = t; i < n4; i += 1024) {
    uint4 kv = key4[i];
    if ((kv.x >> 22) == B) { unsigned p = atomicAdd(&sh_cnt, 1u); if (p < RCAP) cand[p] = kv.x; }
    if ((kv.y >> 22) == B) { unsigned p = atomicAdd(&sh_cnt, 1u); if (p < RCAP) cand[p] = kv.y; }
    if ((kv.z >> 22) == B) { unsigned p = atomicAdd(&sh_cnt, 1u); if (p < RCAP) cand[p] = kv.z; }
    if ((kv.w >> 22) == B) { unsigned p = atomicAdd(&sh_cnt, 1u); if (p < RCAP) cand[p] = kv.w; }
  }
  __syncthreads();
  int cnt = (int)sh_cnt; if (cnt > RCAP) cnt = RCAP;
  if (t == 0) { sh_prefix = 0u; sh_remain = (unsigned)remain; }
  __syncthreads();
  // ---- P3b: 4-pass byte refine, PARALLEL pick per pass ----
  for (int pass = 0; pass < 4; ++pass) {
    int shift = 24 - pass * 8;
    unsigned prefix = sh_prefix;          // stable: last write was before a barrier
    unsigned rem = sh_remain;             // captured BEFORE any write this pass
    if (t < 256) hist256[t] = 0u;
    __syncthreads();
    unsigned himask = (pass == 0) ? 0u : (0xFFFFFFFFu << (shift + 8));
    for (int i = t; i < cnt; i += 1024) {
      unsigned kky = cand[i];
      if ((kky & himask) == prefix) atomicAdd(&hist256[(kky >> shift) & 255u], 1u);
    }
    __syncthreads();
    int pval = (t < 256) ? (int)hist256[t] : 0;
    if (t < 256) sscan[t] = pval;
    __syncthreads();
    for (int off = 1; off < 256; off <<= 1) {
      int o = (t < 256 && t >= off) ? sscan[t - off] : 0;
      __syncthreads();
      if (t < 256) { pval += o; sscan[t] = pval; }
      __syncthreads();
    }
    if (t < 256) {
      unsigned tot = (unsigned)sscan[255];
      unsigned hv = hist256[t];
      unsigned sstrict = tot - (unsigned)pval;   // count in bins > t
      if (sstrict < rem && sstrict + hv >= rem) {
        sh_prefix = prefix | ((unsigned)t << shift);
        sh_remain = rem - sstrict;
      }
    }
    __syncthreads();
  }
  unsigned T = sh_prefix;
  int Gt = (int)(above + (unsigned)remain - sh_remain);   // #{key > T}
  int need = kk - Gt;
  // ---- P4: ballot-ordered compaction (index-ascending, deterministic) ----
  if (t == 0) { sh_bg = 0; sh_be = 0; }
  __syncthreads();
  int lane = t & 63, wid = t >> 6;
  unsigned long long lmask = (1ull << lane) - 1ull;
  for (int start = 0; start < n; start += 1024) {
    int i = start + t;
    unsigned kv = (i < n) ? key[i] : 0u;
    bool g = (i < n) && (kv > T);
    bool e = (i < n) && (kv == T);
    unsigned long long mg = __ballot(g);
    unsigned long long me = __ballot(e);
    if (lane == 0) { wsum_g[wid] = __popcll(mg); wsum_e[wid] = __popcll(me); }
    __syncthreads();
    int pg = 0, pe = 0, tot_g = 0, tot_e = 0;
#pragma unroll
    for (int w2 = 0; w2 < 16; ++w2) {
      int sg = wsum_g[w2], se = wsum_e[w2];
      if (w2 < wid) { pg += sg; pe += se; }
      tot_g += sg; tot_e += se;
    }
    int bg = sh_bg, be = sh_be;
    if (g) perm[bg + pg + __popcll(mg & lmask)] = i;
    if (e) {
      int ep = be + pe + __popcll(me & lmask);
      if (ep < need) perm[Gt + ep] = i;
    }
    __syncthreads();                       // all reads of sh_bg/sh_be done
    if (t == 0) { sh_bg = bg + tot_g; sh_be = be + tot_e; }
  }
  __syncthreads();
  // ---- P5-7: grid build for KNN (skip on last layer) ----
  if (cells > 0) {
    for (int c = t; c < cells; c += 1024) lcnt[c] = 0;
    __syncthreads();
    for (int j = t; j < kk; j += 1024) {
      int node = perm[j];
      float px = pos_in[node * 2], py = pos_in[node * 2 + 1];
      int cx = min(Gg - 1, max(0, (int)(px * inv_w)));
      int cy = min(Gg - 1, max(0, (int)(py * inv_w)));
      atomicAdd(&lcnt[cy * Gg + cx], 1);
    }
    __syncthreads();
    {
      int c0[4]; int base = t * 4; int s = 0;
#pragma unroll
      for (int u = 0; u < 4; ++u) {
        int idx = base + u;
        c0[u] = (idx < cells) ? lcnt[idx] : 0;
        s += c0[u];
      }
      sscan[t] = s;
      __syncthreads();
      int vv = s;
      for (int off = 1; off < 1024; off <<= 1) {
        int o = (t >= off) ? sscan[t - off] : 0;
        __syncthreads();
        vv += o;
        sscan[t] = vv;
        __syncthreads();
      }
      int excl = vv - s;
#pragma unroll
      for (int u = 0; u < 4; ++u) {
        int idx = base + u;
        if (idx < cells) { startsg[idx] = excl; lcur[idx] = excl; countsg[idx] = c0[u]; excl += c0[u]; }
      }
    }
    __syncthreads();
    for (int j = t; j < kk; j += 1024) {
      int node = perm[j];
      float px = pos_in[node * 2], py = pos_in[node * 2 + 1];
      int cx = min(Gg - 1, max(0, (int)(px * inv_w)));
      int cy = min(Gg - 1, max(0, (int)(py * inv_w)));
      int pp = atomicAdd(&lcur[cy * Gg + cx], 1);
      spos[pp] = make_float2(px, py);
      sidx[pp] = j;
    }
  }
}

// ---------- pooled gather + per-block column-max ----------
template <int R>
__global__ __launch_bounds__(256) void k_pool_pmax(
    const float* __restrict__ x, const float* __restrict__ score,
    const int* __restrict__ perm, const float* __restrict__ pos_in,
    float* __restrict__ xout, float* __restrict__ pos_out, int store,
    float* __restrict__ pmax) {
  __shared__ float sm[2][HID];
  int f = threadIdx.x & 127;
  int half = threadIdx.x >> 7;
  int j0 = blockIdx.x * R;
  float mx = -1e30f;
  for (int r = half; r < R; r += 2) {
    int j = j0 + r;
    int node = perm[j];
    float v = score[node];
    float val = x[(size_t)node * HID + f] * v;
    if (store) {
      xout[(size_t)j * HID + f] = val;
      if (f < 2) pos_out[j * 2 + f] = pos_in[node * 2 + f];
    }
    mx = fmaxf(mx, val);
  }
  sm[half][f] = mx;
  __syncthreads();
  if (half == 0) pmax[blockIdx.x * HID + f] = fmaxf(sm[0][f], sm[1][f]);
}

// ---------- exact KNN, one wave per query ----------
template <int K>
__global__ __launch_bounds__(256) void k_knn_wave(const float2* __restrict__ spos,
                           const int* __restrict__ sidx,
                           const int* __restrict__ starts, const int* __restrict__ counts,
                           int m, int G, float w, float inv_w, int* __restrict__ src_out) {
  int lane = threadIdx.x & 63;
  int j = blockIdx.x * (blockDim.x >> 6) + (threadIdx.x >> 6);
  if (j >= m) return;                      // wave-uniform exit
  float2 qp = spos[j];
  int q = sidx[j];
  int cx = min(G - 1, max(0, (int)(qp.x * inv_w)));
  int cy = min(G - 1, max(0, (int)(qp.y * inv_w)));

  float bd[K]; int bi[K];
#pragma unroll
  for (int t = 0; t < K; ++t) { bd[t] = 1e30f; bi[t] = 0; }

  auto scan_span = [&](int s, int e) {
    for (int p = s + lane; p < e; p += 64) {
      if (p == j) continue;                // self (loop=False)
      float2 pp = spos[p];
      float dx = qp.x - pp.x, dy = qp.y - pp.y;
      float d = dx * dx + dy * dy;
      if (d < bd[K - 1]) {
        float dd = d; int ii = sidx[p];
#pragma unroll
        for (int t = 0; t < K; ++t) {
          bool sw = dd < bd[t];
          float od = bd[t]; int oi = bi[t];
          if (sw) { bd[t] = dd; bi[t] = ii; dd = od; ii = oi; }
        }
      }
    }
  };

  {
    int xl = max(0, cx - 1), xh = min(G - 1, cx + 1);
    int y0 = max(0, cy - 1), y1 = min(G - 1, cy + 1);
    int ss[3], ee[3]; int nr = 0;
    for (int y = y0; y <= y1; ++y) {
      int b = y * G;
      ss[nr] = starts[b + xl];
      ee[nr] = starts[b + xh] + counts[b + xh];
      ++nr;
    }
    for (int t = 0; t < nr; ++t) scan_span(ss[t], ee[t]);
  }

  int r = 1;
  unsigned long long mg[K];
  while (true) {
    unsigned long long tmp[K];
#pragma unroll
    for (int t = 0; t < K; ++t)
      tmp[t] = ((unsigned long long)__float_as_uint(bd[t]) << 32) | (unsigned)bi[t];
#pragma unroll
    for (int t = 0; t < K; ++t) {
      unsigned long long mn = tmp[0];
#pragma unroll
      for (int o = 1; o < 64; o <<= 1) {
        unsigned long long ot = __shfl_xor(mn, o, 64);
        if (ot < mn) mn = ot;
      }
      mg[t] = mn;
      if (tmp[0] == mn) {
#pragma unroll
        for (int s2 = 0; s2 < K - 1; ++s2) tmp[s2] = tmp[s2 + 1];
        tmp[K - 1] = ~0ull;
      }
    }
    float kth = __uint_as_float((unsigned)(mg[K - 1] >> 32));
    float bnd = 1e30f;
    if (cx - r > 0)     bnd = fminf(bnd, qp.x - (float)(cx - r) * w);
    if (cx + r < G - 1) bnd = fminf(bnd, (float)(cx + r + 1) * w - qp.x);
    if (cy - r > 0)     bnd = fminf(bnd, qp.y - (float)(cy - r) * w);
    if (cy + r < G - 1) bnd = fminf(bnd, (float)(cy + r + 1) * w - qp.y);
    if (bnd > 1e29f) break;                // grid exhausted
    float bb = fmaxf(bnd, 0.f) * 0.999f;
    if (kth < bb * bb) break;
    ++r;
    int xl = max(0, cx - r), xh = min(G - 1, cx + r);
    int yt = cy - r, yb = cy + r;
    if (yt >= 0)     { int b = yt * G; scan_span(starts[b + xl], starts[b + xh] + counts[b + xh]); }
    if (yb <= G - 1) { int b = yb * G; scan_span(starts[b + xl], starts[b + xh] + counts[b + xh]); }
    int ylo = max(0, cy - r + 1), yhi = min(G - 1, cy + r - 1);
    for (int y = ylo; y <= yhi; ++y) {
      int b = y * G;
      if (cx - r >= 0)     { int c = b + cx - r; scan_span(starts[c], starts[c] + counts[c]); }
      if (cx + r <= G - 1) { int c = b + cx + r; scan_span(starts[c], starts[c] + counts[c]); }
    }
  }
  if (lane == 0) {
#pragma unroll
    for (int t = 0; t < K; ++t) src_out[q * K + t] = (int)(unsigned)(mg[t] & 0xffffffffu);
  }
}

// ---------- final: reduce pmax segments -> xs, then MLP head ----------
__global__ __launch_bounds__(1024) void k_final(const float* __restrict__ pmax,
                        int P0, int P1, int P2,
                        const float* __restrict__ W1, const float* __restrict__ b1,
                        const float* __restrict__ W2, const float* __restrict__ b2,
                        float* __restrict__ out) {
  __shared__ float red[8][HID];
  __shared__ float sxs[3 * HID];
  __shared__ float h1[HID];
  int f = threadIdx.x & 127, ch = threadIdx.x >> 7;   // 1024 threads
  int off0 = 0, off1 = P0, off2 = P0 + P1, off3 = P0 + P1 + P2;
  int lo[3] = {off0, off1, off2};
  int hi[3] = {off1, off2, off3};
  for (int l = 0; l < 3; ++l) {
    float mx = -1e30f;
    for (int p = lo[l] + ch; p < hi[l]; p += 8) mx = fmaxf(mx, pmax[p * HID + f]);
    red[ch][f] = mx;
    __syncthreads();
    if (ch == 0) {
      float m2 = red[0][f];
#pragma unroll
      for (int u = 1; u < 8; ++u) m2 = fmaxf(m2, red[u][f]);
      sxs[l * HID + f] = m2;
    }
    __syncthreads();
  }
  if (threadIdx.x < HID) {
    float acc = b1[f];
    for (int c = 0; c < 3 * HID; ++c) acc += sxs[c] * W1[c * HID + f];
    h1[f] = acc > 0.f ? acc : 0.f;
  }
  __syncthreads();
  if (threadIdx.x < 5) {
    float a = b2[threadIdx.x];
    for (int c = 0; c < HID; ++c) a += h1[c] * W2[c * 5 + threadIdx.x];
    out[threadIdx.x] = a;
  }
}

extern "C" void kernel_launch(void* const* d_in, const int* in_sizes, int n_in,
                              void* d_out, int out_size, void* d_ws, size_t ws_size,
                              hipStream_t stream) {
  const float* x_in   = (const float*)d_in[0];
  const float* pos_in = (const float*)d_in[1];
  const int*   ei     = (const int*)d_in[2];
  const float* Wrel   = (const float*)d_in[3];
  const float* brel   = (const float*)d_in[4];
  const float* Wroot  = (const float*)d_in[5];
  const float* Wprel  = (const float*)d_in[6];
  const float* bprel  = (const float*)d_in[7];
  const float* Wproot = (const float*)d_in[8];
  const float* W1     = (const float*)d_in[9];
  const float* b1     = (const float*)d_in[10];
  const float* W2     = (const float*)d_in[11];
  const float* b2     = (const float*)d_in[12];
  float* out = (float*)d_out;

  const int N0 = in_sizes[0] / HID;   // 20000
  const int P0 = (N0 / 2) / PR, P1 = (N0 / 4) / PR, P2 = (N0 / 8) / PR;  // 500/250/125

  // workspace layout (16B-aligned regions)
  char* w = (char*)d_ws;
  float*    xB     = (float*)w;    w += (size_t)N0 * HID * 4;
  float*    xA     = (float*)w;    w += (size_t)(N0 / 2) * HID * 4;
  float*    score  = (float*)w;    w += (size_t)N0 * 4;
  unsigned* key    = (unsigned*)w; w += (size_t)N0 * 4;
  float*    ubuf   = (float*)w;    w += (size_t)N0 * 4;
  float*    vbuf   = (float*)w;    w += (size_t)N0 * 4;
  float*    posA   = (float*)w;    w += (size_t)(N0 / 2) * 2 * 4;
  float*    posB   = (float*)w;    w += (size_t)(N0 / 2) * 2 * 4;
  int*      srcbuf = (int*)w;      w += (size_t)(N0 / 2) * 8 * 4;
  int*      permb  = (int*)w;      w += (size_t)(N0 / 2) * 4;
  float*    pmax   = (float*)w;    w += (size_t)(P0 + P1 + P2) * HID * 4;
  int*      counts = (int*)w;      w += MAXCELLS * 4;
  int*      starts = (int*)w;      w += MAXCELLS * 4;
  float2*   spos   = (float2*)w;   w += (size_t)(N0 / 2) * 8;
  int*      sidx   = (int*)w;      w += (size_t)(N0 / 2) * 4;
  (void)ws_size; (void)n_in; (void)out_size;

  int n = N0;
  const float* xcur   = x_in;
  const float* poscur = pos_in;
  const int*   srccur = ei;
  int kcur = 6;                 // E0/N0 == 6 (K0)
  int Poff = 0;

  for (int l = 0; l < 3; ++l) {
    const int kk = n / 2;
    int Gg = (int)ceilf(sqrtf((float)kk / 2.5f));
    if (Gg > 64) Gg = 64;
    if (Gg < 1) Gg = 1;
    int cells = Gg * Gg;
    float cw = 100.f / (float)Gg;
    float inv_w = (float)Gg / 100.f;
    int cblocks = (n + CRPB - 1) / CRPB;

    if (kcur == 6) {
      k_conv_fused<6><<<cblocks, 128, 0, stream>>>(xcur, srccur, n, 1.f / 6.f,
          Wrel + l * HID * HID, Wroot + l * HID * HID, brel + l * HID,
          Wprel + l * HID, Wproot + l * HID, xB, ubuf, vbuf);
      k_score_lite<6><<<(n + 255) / 256, 256, 0, stream>>>(ubuf, vbuf, srccur, bprel + l,
                                                           n, score, key);
    } else {
      k_conv_fused<8><<<cblocks, 128, 0, stream>>>(xcur, srccur, n, 1.f / 8.f,
          Wrel + l * HID * HID, Wroot + l * HID * HID, brel + l * HID,
          Wprel + l * HID, Wproot + l * HID, xB, ubuf, vbuf);
      k_score_lite<8><<<(n + 255) / 256, 256, 0, stream>>>(ubuf, vbuf, srccur, bprel + l,
                                                           n, score, key);
    }
    k_select<<<1, 1024, 0, stream>>>(key, n, kk, poscur, permb, starts, counts,
                                     spos, sidx, (l < 2) ? cells : 0, Gg, inv_w);
    float* pos_out = (l == 0) ? posA : posB;
    int store = (l < 2) ? 1 : 0;
    k_pool_pmax<PR><<<kk / PR, 256, 0, stream>>>(xB, score, permb, poscur, xA, pos_out,
                                                 store, pmax + (size_t)Poff * HID);
    Poff += kk / PR;
    n = kk;
    if (l == 0)      { k_knn_wave<6><<<(n + 3) / 4, 256, 0, stream>>>(spos, sidx, starts, counts,
                                                                      n, Gg, cw, inv_w, srcbuf); kcur = 6; }
    else if (l == 1) { k_knn_wave<8><<<(n + 3) / 4, 256, 0, stream>>>(spos, sidx, starts, counts,
                                                                      n, Gg, cw, inv_w, srcbuf); kcur = 8; }
    xcur = xA; poscur = pos_out; srccur = srcbuf;
  }
  k_final<<<1, 1024, 0, stream>>>(pmax, P0, P1, P2, W1, b1, W2, b2, out);
}

// Round 12
// 310.251 us; speedup vs baseline: 1.2414x; 1.0341x over previous
//
#include <hip/hip_runtime.h>
#include <hip/hip_bf16.h>
#include <math.h>

#define HID 128
#define PR 20     // rows per pool block (divides 10000/5000/2500)
#define CRPB 32   // conv rows per block
#define RCAP 6144 // radix candidate cap
#define MAXCELLS 4096

__device__ inline int wave_iscan(int v, int lane) {   // inclusive scan within 64-lane wave
#pragma unroll
  for (int off = 1; off < 64; off <<= 1) {
    int o = __shfl_up(v, off, 64);
    if (lane >= off) v += o;
  }
  return v;
}

// ---------- fused mean-gather + GraphConv + score-scalar epilogue ----------
template <int K>
__global__ __launch_bounds__(128) void k_conv_fused(
    const float* __restrict__ x, const int* __restrict__ src, int n, float invk,
    const float* __restrict__ Wrel, const float* __restrict__ Wroot,
    const float* __restrict__ brel,
    const float* __restrict__ wprel, const float* __restrict__ wproot,
    float* __restrict__ out, float* __restrict__ uo, float* __restrict__ vo) {
  __shared__ float4 sagg4[CRPB][HID / 4];
  __shared__ float4 sx4[CRPB][HID / 4];
  __shared__ int ssrc[CRPB * K];
  int t = threadIdx.x;
  int i0 = blockIdx.x * CRPB;
  const int nK = n * K;
  for (int s = t; s < CRPB * K; s += 128) {
    int gi = i0 * K + s;
    int v = (gi < nK) ? src[gi] : 0;
    ssrc[s] = ((unsigned)v < (unsigned)n) ? v : 0;
  }
  __syncthreads();
  {
    int fq = t & 31, h = t >> 5;                // col quad, row slot (4 slots)
    const float4* x4 = (const float4*)x;
    for (int r = h; r < CRPB; r += 4) {
      int row = i0 + r;
      float4 s = make_float4(0.f, 0.f, 0.f, 0.f);
      float4 xv = make_float4(0.f, 0.f, 0.f, 0.f);
      if (row < n) {
#pragma unroll
        for (int j = 0; j < K; ++j) {
          float4 xx = x4[(size_t)ssrc[r * K + j] * 32 + fq];
          s.x += xx.x; s.y += xx.y; s.z += xx.z; s.w += xx.w;
        }
        xv = x4[(size_t)row * 32 + fq];
      }
      s.x *= invk; s.y *= invk; s.z *= invk; s.w *= invk;
      sagg4[r][fq] = s;
      sx4[r][fq] = xv;
    }
  }
  __syncthreads();
  int q = t & 31, rg = t >> 5;
  const float4* Wrel4  = (const float4*)Wrel;
  const float4* Wroot4 = (const float4*)Wroot;
  float4 bq = ((const float4*)brel)[q];
  float4 acc[8];
#pragma unroll
  for (int rr = 0; rr < 8; ++rr) acc[rr] = bq;
  int rbase = rg * 8;
#pragma unroll 2
  for (int cq = 0; cq < HID / 4; ++cq) {
    float4 w1[4], w2[4];
#pragma unroll
    for (int uu = 0; uu < 4; ++uu) {
      w1[uu] = Wrel4[(cq * 4 + uu) * 32 + q];
      w2[uu] = Wroot4[(cq * 4 + uu) * 32 + q];
    }
#pragma unroll
    for (int rr = 0; rr < 8; ++rr) {
      float4 a  = sagg4[rbase + rr][cq];
      float4 xx = sx4[rbase + rr][cq];
      acc[rr].x += a.x*w1[0].x + a.y*w1[1].x + a.z*w1[2].x + a.w*w1[3].x
                 + xx.x*w2[0].x + xx.y*w2[1].x + xx.z*w2[2].x + xx.w*w2[3].x;
      acc[rr].y += a.x*w1[0].y + a.y*w1[1].y + a.z*w1[2].y + a.w*w1[3].y
                 + xx.x*w2[0].y + xx.y*w2[1].y + xx.z*w2[2].y + xx.w*w2[3].y;
      acc[rr].z += a.x*w1[0].z + a.y*w1[1].z + a.z*w1[2].z + a.w*w1[3].z
                 + xx.x*w2[0].z + xx.y*w2[1].z + xx.z*w2[2].z + xx.w*w2[3].z;
      acc[rr].w += a.x*w1[0].w + a.y*w1[1].w + a.z*w1[2].w + a.w*w1[3].w
                 + xx.x*w2[0].w + xx.y*w2[1].w + xx.z*w2[2].w + xx.w*w2[3].w;
    }
  }
  float4 wplq = ((const float4*)wprel)[q];
  float4 wprq = ((const float4*)wproot)[q];
#pragma unroll
  for (int rr = 0; rr < 8; ++rr) {
    int row = i0 + rbase + rr;
    float4 v = acc[rr];
    v.x = v.x > 0.f ? v.x : 0.f;
    v.y = v.y > 0.f ? v.y : 0.f;
    v.z = v.z > 0.f ? v.z : 0.f;
    v.w = v.w > 0.f ? v.w : 0.f;
    float pu = 0.f, pv = 0.f;
    if (row < n) {
      ((float4*)out)[(size_t)row * 32 + q] = v;
      pu = v.x * wplq.x + v.y * wplq.y + v.z * wplq.z + v.w * wplq.w;
      pv = v.x * wprq.x + v.y * wprq.y + v.z * wprq.z + v.w * wprq.w;
    }
#pragma unroll
    for (int o = 16; o; o >>= 1) {
      pu += __shfl_down(pu, o, 32);
      pv += __shfl_down(pv, o, 32);
    }
    if (q == 0 && row < n) { uo[row] = pu; vo[row] = pv; }
  }
}

// ---------- scalar score ----------
template <int K>
__global__ void k_score_lite(const float* __restrict__ u, const float* __restrict__ v,
                             const int* __restrict__ src, const float* __restrict__ bprel,
                             int n, float* __restrict__ score, unsigned* __restrict__ key) {
  int i = blockIdx.x * blockDim.x + threadIdx.x;
  if (i >= n) return;
  float s = v[i] + bprel[0];
#pragma unroll
  for (int j = 0; j < K; ++j) s += u[src[i * K + j]];
  float sc = tanhf(s);
  score[i] = sc;
  unsigned bb = __float_as_uint(sc);
  key[i] = (bb & 0x80000000u) ? ~bb : (bb | 0x80000000u);
}

// ---------- mega-select: barrier-minimal (wave-shuffle scans everywhere) ----------
__global__ __launch_bounds__(1024) void k_select(
    const unsigned* __restrict__ key, int n, int kk,
    const float* __restrict__ pos_in, int* __restrict__ perm,
    int* __restrict__ startsg, int* __restrict__ countsg,
    float2* __restrict__ spos, int* __restrict__ sidx,
    int cells, int Gg, float inv_w) {
  __shared__ unsigned hist[1024];
  __shared__ unsigned cand[RCAP];
  __shared__ unsigned hist256[256];
  __shared__ int lcnt[MAXCELLS];
  __shared__ int lcur[MAXCELLS];
  __shared__ unsigned sh_B, sh_above, sh_cnt, sh_remain, sh_prefix;
  __shared__ int wtA[16], wtB[16];
  int t = threadIdx.x;
  int lane = t & 63, wid = t >> 6;

  // ---- P1: 1024-bin histogram over top 10 bits ----
  hist[t] = 0u;
  if (t == 0) sh_cnt = 0u;
  __syncthreads();
  const uint4* key4 = (const uint4*)key;
  int n4 = n >> 2;                        // n divisible by 4
  for (int i = t; i < n4; i += 1024) {
    uint4 kv = key4[i];
    atomicAdd(&hist[kv.x >> 22], 1u);
    atomicAdd(&hist[kv.y >> 22], 1u);
    atomicAdd(&hist[kv.z >> 22], 1u);
    atomicAdd(&hist[kv.w >> 22], 1u);
  }
  __syncthreads();
  // ---- P2: boundary-bin pick via shuffle scan (1 barrier) ----
  {
    unsigned hv = hist[t];
    int iv = wave_iscan((int)hv, lane);
    if (lane == 63) wtA[wid] = iv;
    __syncthreads();
    int b = 0, tot = 0;
#pragma unroll
    for (int w2 = 0; w2 < 16; ++w2) { int s = wtA[w2]; if (w2 < wid) b += s; tot += s; }
    unsigned val = (unsigned)(iv + b);
    unsigned above_strict = (unsigned)tot - val;
    unsigned above_incl = above_strict + hv;
    if (above_incl >= (unsigned)kk && above_strict < (unsigned)kk) {
      sh_B = (unsigned)t;
      sh_above = above_strict;
    }
    __syncthreads();
  }
  unsigned B = sh_B, above = sh_above;
  int remain = kk - (int)above;
  // ---- P3: collect bin-B candidates ----
  for (int i = t; i < n4; i += 1024) {
    uint4 kv = key4[i];
    if ((kv.x >> 22) == B) { unsigned p = atomicAdd(&sh_cnt, 1u); if (p < RCAP) cand[p] = kv.x; }
    if ((kv.y >> 22) == B) { unsigned p = atomicAdd(&sh_cnt, 1u); if (p < RCAP) cand[p] = kv.y; }
    if ((kv.z >> 22) == B) { unsigned p = atomicAdd(&sh_cnt, 1u); if (p < RCAP) cand[p] = kv.z; }
    if ((kv.w >> 22) == B) { unsigned p = atomicAdd(&sh_cnt, 1u); if (p < RCAP) cand[p] = kv.w; }
  }
  __syncthreads();
  int cnt = (int)sh_cnt; if (cnt > RCAP) cnt = RCAP;
  if (t == 0) { sh_prefix = 0u; sh_remain = (unsigned)remain; }
  __syncthreads();
  // ---- P3b: 4-pass byte refine, shuffle-scan pick (4 barriers/pass) ----
  for (int pass = 0; pass < 4; ++pass) {
    int shift = 24 - pass * 8;
    unsigned prefix = sh_prefix;          // stable since last barrier
    unsigned rem = sh_remain;
    if (t < 256) hist256[t] = 0u;
    __syncthreads();
    unsigned himask = (pass == 0) ? 0u : (0xFFFFFFFFu << (shift + 8));
    for (int i = t; i < cnt; i += 1024) {
      unsigned kky = cand[i];
      if ((kky & himask) == prefix) atomicAdd(&hist256[(kky >> shift) & 255u], 1u);
    }
    __syncthreads();
    int hv = (t < 256) ? (int)hist256[t] : 0;
    int iv = wave_iscan(hv, lane);
    if (t < 256 && lane == 63) wtB[wid] = iv;   // wid 0..3
    __syncthreads();
    if (t < 256) {
      int b = 0, tot = 0;
#pragma unroll
      for (int w2 = 0; w2 < 4; ++w2) { int s = wtB[w2]; if (w2 < wid) b += s; tot += s; }
      unsigned val = (unsigned)(iv + b);
      unsigned sstrict = (unsigned)tot - val;
      if (sstrict < rem && sstrict + (unsigned)hv >= rem) {
        sh_prefix = prefix | ((unsigned)t << shift);
        sh_remain = rem - sstrict;
      }
    }
    __syncthreads();
  }
  unsigned T = sh_prefix;
  int Gt = (int)(above + (unsigned)remain - sh_remain);   // #{key > T}
  int need = kk - Gt;
  // ---- P4: strided-count compaction (1 barrier; deterministic thread-strided order) ----
  {
    int cg = 0, ce = 0;
    for (int i = t; i < n; i += 1024) {
      unsigned kv = key[i];
      cg += (kv > T);
      ce += (kv == T);
    }
    int ig = wave_iscan(cg, lane);
    int ie = wave_iscan(ce, lane);
    if (lane == 63) { wtA[wid] = ig; wtB[wid] = ie; }
    __syncthreads();
    int bg = 0, be = 0;
#pragma unroll
    for (int w2 = 0; w2 < 16; ++w2) { if (w2 < wid) { bg += wtA[w2]; be += wtB[w2]; } }
    int og = bg + ig - cg;                // exclusive prefix
    int oe = be + ie - ce;
    for (int i = t; i < n; i += 1024) {
      unsigned kv = key[i];
      if (kv > T) {
        perm[og++] = i;
      } else if (kv == T) {
        if (oe < need) perm[Gt + oe] = i;
        ++oe;
      }
    }
  }
  __syncthreads();
  // ---- P5-7: grid build for KNN (skip on last layer) ----
  if (cells > 0) {
    for (int c = t; c < cells; c += 1024) lcnt[c] = 0;
    __syncthreads();
    for (int j = t; j < kk; j += 1024) {
      int node = perm[j];
      float px = pos_in[node * 2], py = pos_in[node * 2 + 1];
      int cx = min(Gg - 1, max(0, (int)(px * inv_w)));
      int cy = min(Gg - 1, max(0, (int)(py * inv_w)));
      atomicAdd(&lcnt[cy * Gg + cx], 1);
    }
    __syncthreads();
    {
      int c0[4]; int base4 = t * 4; int s = 0;
#pragma unroll
      for (int u = 0; u < 4; ++u) {
        int idx = base4 + u;
        c0[u] = (idx < cells) ? lcnt[idx] : 0;
        s += c0[u];
      }
      int is = wave_iscan(s, lane);
      if (lane == 63) wtA[wid] = is;
      __syncthreads();
      int b = 0;
#pragma unroll
      for (int w2 = 0; w2 < 16; ++w2) { if (w2 < wid) b += wtA[w2]; }
      int excl = b + is - s;
#pragma unroll
      for (int u = 0; u < 4; ++u) {
        int idx = base4 + u;
        if (idx < cells) { startsg[idx] = excl; lcur[idx] = excl; countsg[idx] = c0[u]; excl += c0[u]; }
      }
    }
    __syncthreads();
    for (int j = t; j < kk; j += 1024) {
      int node = perm[j];
      float px = pos_in[node * 2], py = pos_in[node * 2 + 1];
      int cx = min(Gg - 1, max(0, (int)(px * inv_w)));
      int cy = min(Gg - 1, max(0, (int)(py * inv_w)));
      int pp = atomicAdd(&lcur[cy * Gg + cx], 1);
      spos[pp] = make_float2(px, py);
      sidx[pp] = j;
    }
  }
}

// ---------- pooled gather + per-block column-max ----------
template <int R>
__global__ __launch_bounds__(256) void k_pool_pmax(
    const float* __restrict__ x, const float* __restrict__ score,
    const int* __restrict__ perm, const float* __restrict__ pos_in,
    float* __restrict__ xout, float* __restrict__ pos_out, int store,
    float* __restrict__ pmax) {
  __shared__ float sm[2][HID];
  int f = threadIdx.x & 127;
  int half = threadIdx.x >> 7;
  int j0 = blockIdx.x * R;
  float mx = -1e30f;
  for (int r = half; r < R; r += 2) {
    int j = j0 + r;
    int node = perm[j];
    float v = score[node];
    float val = x[(size_t)node * HID + f] * v;
    if (store) {
      xout[(size_t)j * HID + f] = val;
      if (f < 2) pos_out[j * 2 + f] = pos_in[node * 2 + f];
    }
    mx = fmaxf(mx, val);
  }
  sm[half][f] = mx;
  __syncthreads();
  if (half == 0) pmax[blockIdx.x * HID + f] = fmaxf(sm[0][f], sm[1][f]);
}

// ---------- exact KNN, one wave per query ----------
template <int K>
__global__ __launch_bounds__(256) void k_knn_wave(const float2* __restrict__ spos,
                           const int* __restrict__ sidx,
                           const int* __restrict__ starts, const int* __restrict__ counts,
                           int m, int G, float w, float inv_w, int* __restrict__ src_out) {
  int lane = threadIdx.x & 63;
  int j = blockIdx.x * (blockDim.x >> 6) + (threadIdx.x >> 6);
  if (j >= m) return;
  float2 qp = spos[j];
  int q = sidx[j];
  int cx = min(G - 1, max(0, (int)(qp.x * inv_w)));
  int cy = min(G - 1, max(0, (int)(qp.y * inv_w)));

  float bd[K]; int bi[K];
#pragma unroll
  for (int t = 0; t < K; ++t) { bd[t] = 1e30f; bi[t] = 0; }

  auto scan_span = [&](int s, int e) {
    for (int p = s + lane; p < e; p += 64) {
      if (p == j) continue;
      float2 pp = spos[p];
      float dx = qp.x - pp.x, dy = qp.y - pp.y;
      float d = dx * dx + dy * dy;
      if (d < bd[K - 1]) {
        float dd = d; int ii = sidx[p];
#pragma unroll
        for (int t = 0; t < K; ++t) {
          bool sw = dd < bd[t];
          float od = bd[t]; int oi = bi[t];
          if (sw) { bd[t] = dd; bi[t] = ii; dd = od; ii = oi; }
        }
      }
    }
  };

  {
    int xl = max(0, cx - 1), xh = min(G - 1, cx + 1);
    int y0 = max(0, cy - 1), y1 = min(G - 1, cy + 1);
    int ss[3], ee[3]; int nr = 0;
    for (int y = y0; y <= y1; ++y) {
      int b = y * G;
      ss[nr] = starts[b + xl];
      ee[nr] = starts[b + xh] + counts[b + xh];
      ++nr;
    }
    for (int t = 0; t < nr; ++t) scan_span(ss[t], ee[t]);
  }

  int r = 1;
  unsigned long long mg[K];
  while (true) {
    unsigned long long tmp[K];
#pragma unroll
    for (int t = 0; t < K; ++t)
      tmp[t] = ((unsigned long long)__float_as_uint(bd[t]) << 32) | (unsigned)bi[t];
#pragma unroll
    for (int t = 0; t < K; ++t) {
      unsigned long long mn = tmp[0];
#pragma unroll
      for (int o = 1; o < 64; o <<= 1) {
        unsigned long long ot = __shfl_xor(mn, o, 64);
        if (ot < mn) mn = ot;
      }
      mg[t] = mn;
      if (tmp[0] == mn) {
#pragma unroll
        for (int s2 = 0; s2 < K - 1; ++s2) tmp[s2] = tmp[s2 + 1];
        tmp[K - 1] = ~0ull;
      }
    }
    float kth = __uint_as_float((unsigned)(mg[K - 1] >> 32));
    float bnd = 1e30f;
    if (cx - r > 0)     bnd = fminf(bnd, qp.x - (float)(cx - r) * w);
    if (cx + r < G - 1) bnd = fminf(bnd, (float)(cx + r + 1) * w - qp.x);
    if (cy - r > 0)     bnd = fminf(bnd, qp.y - (float)(cy - r) * w);
    if (cy + r < G - 1) bnd = fminf(bnd, (float)(cy + r + 1) * w - qp.y);
    if (bnd > 1e29f) break;
    float bb = fmaxf(bnd, 0.f) * 0.999f;
    if (kth < bb * bb) break;
    ++r;
    int xl = max(0, cx - r), xh = min(G - 1, cx + r);
    int yt = cy - r, yb = cy + r;
    if (yt >= 0)     { int b = yt * G; scan_span(starts[b + xl], starts[b + xh] + counts[b + xh]); }
    if (yb <= G - 1) { int b = yb * G; scan_span(starts[b + xl], starts[b + xh] + counts[b + xh]); }
    int ylo = max(0, cy - r + 1), yhi = min(G - 1, cy + r - 1);
    for (int y = ylo; y <= yhi; ++y) {
      int b = y * G;
      if (cx - r >= 0)     { int c = b + cx - r; scan_span(starts[c], starts[c] + counts[c]); }
      if (cx + r <= G - 1) { int c = b + cx + r; scan_span(starts[c], starts[c] + counts[c]); }
    }
  }
  if (lane == 0) {
#pragma unroll
    for (int t = 0; t < K; ++t) src_out[q * K + t] = (int)(unsigned)(mg[t] & 0xffffffffu);
  }
}

// ---------- final: reduce pmax segments -> xs, then MLP head ----------
__global__ __launch_bounds__(1024) void k_final(const float* __restrict__ pmax,
                        int P0, int P1, int P2,
                        const float* __restrict__ W1, const float* __restrict__ b1,
                        const float* __restrict__ W2, const float* __restrict__ b2,
                        float* __restrict__ out) {
  __shared__ float red[8][HID];
  __shared__ float sxs[3 * HID];
  __shared__ float h1[HID];
  int f = threadIdx.x & 127, ch = threadIdx.x >> 7;
  int off0 = 0, off1 = P0, off2 = P0 + P1, off3 = P0 + P1 + P2;
  int lo[3] = {off0, off1, off2};
  int hi[3] = {off1, off2, off3};
  for (int l = 0; l < 3; ++l) {
    float mx = -1e30f;
    for (int p = lo[l] + ch; p < hi[l]; p += 8) mx = fmaxf(mx, pmax[p * HID + f]);
    red[ch][f] = mx;
    __syncthreads();
    if (ch == 0) {
      float m2 = red[0][f];
#pragma unroll
      for (int u = 1; u < 8; ++u) m2 = fmaxf(m2, red[u][f]);
      sxs[l * HID + f] = m2;
    }
    __syncthreads();
  }
  if (threadIdx.x < HID) {
    float acc = b1[f];
    for (int c = 0; c < 3 * HID; ++c) acc += sxs[c] * W1[c * HID + f];
    h1[f] = acc > 0.f ? acc : 0.f;
  }
  __syncthreads();
  if (threadIdx.x < 5) {
    float a = b2[threadIdx.x];
    for (int c = 0; c < HID; ++c) a += h1[c] * W2[c * 5 + threadIdx.x];
    out[threadIdx.x] = a;
  }
}

extern "C" void kernel_launch(void* const* d_in, const int* in_sizes, int n_in,
                              void* d_out, int out_size, void* d_ws, size_t ws_size,
                              hipStream_t stream) {
  const float* x_in   = (const float*)d_in[0];
  const float* pos_in = (const float*)d_in[1];
  const int*   ei     = (const int*)d_in[2];
  const float* Wrel   = (const float*)d_in[3];
  const float* brel   = (const float*)d_in[4];
  const float* Wroot  = (const float*)d_in[5];
  const float* Wprel  = (const float*)d_in[6];
  const float* bprel  = (const float*)d_in[7];
  const float* Wproot = (const float*)d_in[8];
  const float* W1     = (const float*)d_in[9];
  const float* b1     = (const float*)d_in[10];
  const float* W2     = (const float*)d_in[11];
  const float* b2     = (const float*)d_in[12];
  float* out = (float*)d_out;

  const int N0 = in_sizes[0] / HID;   // 20000
  const int P0 = (N0 / 2) / PR, P1 = (N0 / 4) / PR, P2 = (N0 / 8) / PR;

  char* w = (char*)d_ws;
  float*    xB     = (float*)w;    w += (size_t)N0 * HID * 4;
  float*    xA     = (float*)w;    w += (size_t)(N0 / 2) * HID * 4;
  float*    score  = (float*)w;    w += (size_t)N0 * 4;
  unsigned* key    = (unsigned*)w; w += (size_t)N0 * 4;
  float*    ubuf   = (float*)w;    w += (size_t)N0 * 4;
  float*    vbuf   = (float*)w;    w += (size_t)N0 * 4;
  float*    posA   = (float*)w;    w += (size_t)(N0 / 2) * 2 * 4;
  float*    posB   = (float*)w;    w += (size_t)(N0 / 2) * 2 * 4;
  int*      srcbuf = (int*)w;      w += (size_t)(N0 / 2) * 8 * 4;
  int*      permb  = (int*)w;      w += (size_t)(N0 / 2) * 4;
  float*    pmax   = (float*)w;    w += (size_t)(P0 + P1 + P2) * HID * 4;
  int*      counts = (int*)w;      w += MAXCELLS * 4;
  int*      starts = (int*)w;      w += MAXCELLS * 4;
  float2*   spos   = (float2*)w;   w += (size_t)(N0 / 2) * 8;
  int*      sidx   = (int*)w;      w += (size_t)(N0 / 2) * 4;
  (void)ws_size; (void)n_in; (void)out_size;

  int n = N0;
  const float* xcur   = x_in;
  const float* poscur = pos_in;
  const int*   srccur = ei;
  int kcur = 6;
  int Poff = 0;

  for (int l = 0; l < 3; ++l) {
    const int kk = n / 2;
    int Gg = (int)ceilf(sqrtf((float)kk / 2.5f));
    if (Gg > 64) Gg = 64;
    if (Gg < 1) Gg = 1;
    int cells = Gg * Gg;
    float cw = 100.f / (float)Gg;
    float inv_w = (float)Gg / 100.f;
    int cblocks = (n + CRPB - 1) / CRPB;

    if (kcur == 6) {
      k_conv_fused<6><<<cblocks, 128, 0, stream>>>(xcur, srccur, n, 1.f / 6.f,
          Wrel + l * HID * HID, Wroot + l * HID * HID, brel + l * HID,
          Wprel + l * HID, Wproot + l * HID, xB, ubuf, vbuf);
      k_score_lite<6><<<(n + 255) / 256, 256, 0, stream>>>(ubuf, vbuf, srccur, bprel + l,
                                                           n, score, key);
    } else {
      k_conv_fused<8><<<cblocks, 128, 0, stream>>>(xcur, srccur, n, 1.f / 8.f,
          Wrel + l * HID * HID, Wroot + l * HID * HID, brel + l * HID,
          Wprel + l * HID, Wproot + l * HID, xB, ubuf, vbuf);
      k_score_lite<8><<<(n + 255) / 256, 256, 0, stream>>>(ubuf, vbuf, srccur, bprel + l,
                                                           n, score, key);
    }
    k_select<<<1, 1024, 0, stream>>>(key, n, kk, poscur, permb, starts, counts,
                                     spos, sidx, (l < 2) ? cells : 0, Gg, inv_w);
    float* pos_out = (l == 0) ? posA : posB;
    int store = (l < 2) ? 1 : 0;
    k_pool_pmax<PR><<<kk / PR, 256, 0, stream>>>(xB, score, permb, poscur, xA, pos_out,
                                                 store, pmax + (size_t)Poff * HID);
    Poff += kk / PR;
    n = kk;
    if (l == 0)      { k_knn_wave<6><<<(n + 3) / 4, 256, 0, stream>>>(spos, sidx, starts, counts,
                                                                      n, Gg, cw, inv_w, srcbuf); kcur = 6; }
    else if (l == 1) { k_knn_wave<8><<<(n + 3) / 4, 256, 0, stream>>>(spos, sidx, starts, counts,
                                                                      n, Gg, cw, inv_w, srcbuf); kcur = 8; }
    xcur = xA; poscur = pos_out; srccur = srcbuf;
  }
  k_final<<<1, 1024, 0, stream>>>(pmax, P0, P1, P2, W1, b1, W2, b2, out);
}